// Round 1
// baseline (716.723 us; speedup 1.0000x reference)
//
#include <hip/hip_runtime.h>
#include <cstdint>

// TCNN multiresolution hash-grid encoding, forward.
// INPUT_DIM=3, NUM_LEVELS=8, LEVEL_DIM=2, base_res=16, per_level_scale=2.0,
// hashmap = 2^19 entries/level. BATCH = 2^21 points.
// Levels 0..2 (res 16,32,64) dense-indexed; levels 3..7 hashed (xor-prime).

constexpr int      kBatch    = 2097152;
constexpr uint32_t kHashSize = 1u << 19;
constexpr int      kLevels   = 8;

__global__ __launch_bounds__(256) void tcnn_grid_fwd(
    const float* __restrict__ xs,     // [B,3]
    const float* __restrict__ table,  // [8, 2^19, 2]
    float* __restrict__ out)          // [B,16]
{
    const int p = blockIdx.x * 256 + threadIdx.x;

    const float px = xs[3 * p + 0];
    const float py = xs[3 * p + 1];
    const float pz = xs[3 * p + 2];

    float o[2 * kLevels];

#pragma unroll
    for (int l = 0; l < kLevels; ++l) {
        const uint32_t res   = 16u << l;          // 16,32,...,2048
        const bool     dense = (l < 3);           // res^3 <= 2^19
        const float    scale = (float)(res - 1u); // tcnn grid_scale

        const float fx = px * scale + 0.5f;
        const float fy = py * scale + 0.5f;
        const float fz = pz * scale + 0.5f;
        const float flx = floorf(fx), fly = floorf(fy), flz = floorf(fz);
        const float rx = fx - flx, ry = fy - fly, rz = fz - flz;
        const uint32_t bx = (uint32_t)flx;
        const uint32_t by = (uint32_t)fly;
        const uint32_t bz = (uint32_t)flz;

        const float* __restrict__ tl =
            table + (size_t)l * (size_t)kHashSize * 2u;

        float a0 = 0.0f, a1 = 0.0f;
#pragma unroll
        for (int c = 0; c < 8; ++c) {
            const uint32_t ox = c & 1u, oy = (c >> 1) & 1u, oz = (c >> 2) & 1u;
            const uint32_t cx = bx + ox, cy = by + oy, cz = bz + oz;
            uint32_t idx;
            if (dense) {
                idx = cx + cy * res + cz * res * res;
            } else {
                idx = (cx ^ (cy * 2654435761u) ^ (cz * 805459861u)) &
                      (kHashSize - 1u);
            }
            const float2 f =
                *reinterpret_cast<const float2*>(tl + 2u * (size_t)idx);
            const float wx = ox ? rx : 1.0f - rx;
            const float wy = oy ? ry : 1.0f - ry;
            const float wz = oz ? rz : 1.0f - rz;
            const float w  = wx * wy * wz;
            a0 = fmaf(f.x, w, a0);
            a1 = fmaf(f.y, w, a1);
        }
        o[2 * l + 0] = a0;
        o[2 * l + 1] = a1;
    }

    float4* op = reinterpret_cast<float4*>(out + (size_t)p * 16u);
#pragma unroll
    for (int i = 0; i < 4; ++i)
        op[i] = make_float4(o[4 * i + 0], o[4 * i + 1],
                            o[4 * i + 2], o[4 * i + 3]);
}

extern "C" void kernel_launch(void* const* d_in, const int* in_sizes, int n_in,
                              void* d_out, int out_size, void* d_ws,
                              size_t ws_size, hipStream_t stream) {
    const float* xs    = (const float*)d_in[0];
    const float* table = (const float*)d_in[1];
    float*       out   = (float*)d_out;

    dim3 block(256);
    dim3 grid(kBatch / 256);
    hipLaunchKernelGGL(tcnn_grid_fwd, grid, block, 0, stream, xs, table, out);
}

// Round 2
// 444.235 us; speedup vs baseline: 1.6134x; 1.6134x over previous
//
#include <hip/hip_runtime.h>
#include <cstdint>

// TCNN hash-grid encoding, level-split for L2 residency.
// Levels 0-2 dense (res 16/32/64, hot tables 32KB/256KB/2MB) fused in one kernel.
// Levels 3-7 hashed (res 128..2048, 4MB table each) run one kernel per level so
// each XCD's 4MB L2 holds exactly one table. Per-level results go to planar
// float2 arrays in d_ws; a final coalesced kernel interleaves to [B,16].

constexpr int      kBatch    = 2097152;
constexpr uint32_t kHashSize = 1u << 19;

__device__ __forceinline__ void corner_weights(float r, float& w0, float& w1) {
    w0 = 1.0f - r; w1 = r;
}

// ---------------- hashed level ----------------
template <uint32_t RES, int L, bool PLANAR>
__global__ __launch_bounds__(256) void hash_level(
    const float* __restrict__ xs,
    const float* __restrict__ tl,   // this level's table base [2^19, 2]
    float* __restrict__ dst)        // PLANAR: ws plane base; else out
{
    const int p = blockIdx.x * 256 + threadIdx.x;

    const float px = xs[3 * p + 0];
    const float py = xs[3 * p + 1];
    const float pz = xs[3 * p + 2];

    const float scale = (float)(RES - 1u);
    const float fx = px * scale + 0.5f;
    const float fy = py * scale + 0.5f;
    const float fz = pz * scale + 0.5f;
    const float flx = floorf(fx), fly = floorf(fy), flz = floorf(fz);
    const float rx = fx - flx, ry = fy - fly, rz = fz - flz;
    const uint32_t bx = (uint32_t)flx;
    const uint32_t by = (uint32_t)fly;
    const uint32_t bz = (uint32_t)flz;

    const uint32_t hy0 = by * 2654435761u;
    const uint32_t hy1 = (by + 1u) * 2654435761u;
    const uint32_t hz0 = bz * 805459861u;
    const uint32_t hz1 = (bz + 1u) * 805459861u;

    float a0 = 0.0f, a1 = 0.0f;
#pragma unroll
    for (int c = 0; c < 8; ++c) {
        const uint32_t ox = c & 1u, oy = (c >> 1) & 1u, oz = (c >> 2) & 1u;
        const uint32_t idx =
            ((bx + ox) ^ (oy ? hy1 : hy0) ^ (oz ? hz1 : hz0)) & (kHashSize - 1u);
        const float2 f = *reinterpret_cast<const float2*>(tl + 2u * (size_t)idx);
        const float w = (ox ? rx : 1.0f - rx) *
                        (oy ? ry : 1.0f - ry) *
                        (oz ? rz : 1.0f - rz);
        a0 = fmaf(f.x, w, a0);
        a1 = fmaf(f.y, w, a1);
    }

    if (PLANAR) {
        *reinterpret_cast<float2*>(dst + 2u * (size_t)p) = make_float2(a0, a1);
    } else {
        dst[(size_t)p * 16u + 2u * L + 0u] = a0;
        dst[(size_t)p * 16u + 2u * L + 1u] = a1;
    }
}

// ---------------- dense levels 0..2 fused ----------------
template <bool PLANAR>
__global__ __launch_bounds__(256) void dense_levels(
    const float* __restrict__ xs,
    const float* __restrict__ table, // full [8, 2^19, 2]
    float* __restrict__ dst)         // PLANAR: ws base; else out
{
    const int p = blockIdx.x * 256 + threadIdx.x;

    const float px = xs[3 * p + 0];
    const float py = xs[3 * p + 1];
    const float pz = xs[3 * p + 2];

#pragma unroll
    for (int l = 0; l < 3; ++l) {
        const uint32_t res = 16u << l;
        const float scale = (float)(res - 1u);
        const float fx = px * scale + 0.5f;
        const float fy = py * scale + 0.5f;
        const float fz = pz * scale + 0.5f;
        const float flx = floorf(fx), fly = floorf(fy), flz = floorf(fz);
        const float rx = fx - flx, ry = fy - fly, rz = fz - flz;
        const uint32_t bx = (uint32_t)flx;
        const uint32_t by = (uint32_t)fly;
        const uint32_t bz = (uint32_t)flz;

        const float* __restrict__ tl = table + (size_t)l * kHashSize * 2u;

        float a0 = 0.0f, a1 = 0.0f;
#pragma unroll
        for (int c = 0; c < 8; ++c) {
            const uint32_t ox = c & 1u, oy = (c >> 1) & 1u, oz = (c >> 2) & 1u;
            const uint32_t idx =
                (bx + ox) + (by + oy) * res + (bz + oz) * res * res;
            const float2 f =
                *reinterpret_cast<const float2*>(tl + 2u * (size_t)idx);
            const float w = (ox ? rx : 1.0f - rx) *
                            (oy ? ry : 1.0f - ry) *
                            (oz ? rz : 1.0f - rz);
            a0 = fmaf(f.x, w, a0);
            a1 = fmaf(f.y, w, a1);
        }

        if (PLANAR) {
            *reinterpret_cast<float2*>(dst + (size_t)l * kBatch * 2u +
                                       2u * (size_t)p) = make_float2(a0, a1);
        } else {
            dst[(size_t)p * 16u + 2u * l + 0u] = a0;
            dst[(size_t)p * 16u + 2u * l + 1u] = a1;
        }
    }
}

// ---------------- planar -> interleaved [B,16] ----------------
__global__ __launch_bounds__(256) void interleave(
    const float* __restrict__ ws, float* __restrict__ out)
{
    const int p = blockIdx.x * 256 + threadIdx.x;
    float v[16];
#pragma unroll
    for (int l = 0; l < 8; ++l) {
        const float2 t = *reinterpret_cast<const float2*>(
            ws + (size_t)l * kBatch * 2u + 2u * (size_t)p);
        v[2 * l + 0] = t.x;
        v[2 * l + 1] = t.y;
    }
    float4* op = reinterpret_cast<float4*>(out + (size_t)p * 16u);
#pragma unroll
    for (int i = 0; i < 4; ++i)
        op[i] = make_float4(v[4 * i + 0], v[4 * i + 1],
                            v[4 * i + 2], v[4 * i + 3]);
}

extern "C" void kernel_launch(void* const* d_in, const int* in_sizes, int n_in,
                              void* d_out, int out_size, void* d_ws,
                              size_t ws_size, hipStream_t stream) {
    const float* xs    = (const float*)d_in[0];
    const float* table = (const float*)d_in[1];
    float*       out   = (float*)d_out;
    float*       ws    = (float*)d_ws;

    const dim3 block(256);
    const dim3 grid(kBatch / 256);

    const bool planar =
        ws_size >= (size_t)8 * kBatch * 2 * sizeof(float);

    const float* t3 = table + (size_t)3 * kHashSize * 2u;
    const float* t4 = table + (size_t)4 * kHashSize * 2u;
    const float* t5 = table + (size_t)5 * kHashSize * 2u;
    const float* t6 = table + (size_t)6 * kHashSize * 2u;
    const float* t7 = table + (size_t)7 * kHashSize * 2u;

    if (planar) {
        hipLaunchKernelGGL((dense_levels<true>), grid, block, 0, stream,
                           xs, table, ws);
        hipLaunchKernelGGL((hash_level<128u, 3, true>), grid, block, 0, stream,
                           xs, t3, ws + (size_t)3 * kBatch * 2u);
        hipLaunchKernelGGL((hash_level<256u, 4, true>), grid, block, 0, stream,
                           xs, t4, ws + (size_t)4 * kBatch * 2u);
        hipLaunchKernelGGL((hash_level<512u, 5, true>), grid, block, 0, stream,
                           xs, t5, ws + (size_t)5 * kBatch * 2u);
        hipLaunchKernelGGL((hash_level<1024u, 6, true>), grid, block, 0, stream,
                           xs, t6, ws + (size_t)6 * kBatch * 2u);
        hipLaunchKernelGGL((hash_level<2048u, 7, true>), grid, block, 0, stream,
                           xs, t7, ws + (size_t)7 * kBatch * 2u);
        hipLaunchKernelGGL(interleave, grid, block, 0, stream, ws, out);
    } else {
        hipLaunchKernelGGL((dense_levels<false>), grid, block, 0, stream,
                           xs, table, out);
        hipLaunchKernelGGL((hash_level<128u, 3, false>), grid, block, 0, stream,
                           xs, t3, out);
        hipLaunchKernelGGL((hash_level<256u, 4, false>), grid, block, 0, stream,
                           xs, t4, out);
        hipLaunchKernelGGL((hash_level<512u, 5, false>), grid, block, 0, stream,
                           xs, t5, out);
        hipLaunchKernelGGL((hash_level<1024u, 6, false>), grid, block, 0, stream,
                           xs, t6, out);
        hipLaunchKernelGGL((hash_level<2048u, 7, false>), grid, block, 0, stream,
                           xs, t7, out);
    }
}